// Round 1
// baseline (180.849 us; speedup 1.0000x reference)
//
#include <hip/hip_runtime.h>
#include <hip/hip_bf16.h>

// MoE fused block, MI355X gfx950.
// Shapes: B=2, C=256, T*H*W=16384, E=4, K=2. All inputs fp32, output fp32.
//
// R7 -> R8:
//  * MT 64 -> 32 (grid 512 -> 1024 WGs): LDS pool 69.6KB -> 36.9KB so
//    FOUR workgroups fit per CU (32 waves/CU, was 16). The kernel is a
//    barrier chain; with only 2 lockstep WGs/CU the HBM staging phase,
//    the L2-latency-bound GEMM chain and the epilogue burst never
//    overlapped across WGs. 4 independently-phased WGs/CU hide each
//    other's stalls. __launch_bounds__(512,8) caps VGPR at 64 (previous
//    kernel measured exactly 64 with LARGER per-thread state).
//  * Per-wave GEMM shapes halve: GEMM1 mt in {0,1,2}, GEMM2 Mt=2,
//    oacc 16 VGPRs (was 32), staging 16 ch/thread (was 32).
//  * Prepack: reads now fully coalesced (1KB per 32 threads); the
//    fragment scatter moved to the store side (fire-and-forget).

#define C_DIM 256
#define S_DIM 16384          // T*H*W
#define E_DIM 4
#define MT 32                // positions per workgroup
#define XST 264              // Xs/Hs row stride in shorts (16B rows, 33 granules -> odd, bank-friendly)
#define OST 36               // O-tile row stride in floats (16B-aligned, 9 granules -> odd)
#define WFRAG_ELEMS 262144   // elements per prepacked weight tensor (4*16*8*64*8)

typedef __attribute__((ext_vector_type(8))) short bf16x8;
typedef __attribute__((ext_vector_type(4))) float f32x4;

__device__ __forceinline__ short bfq(float f) {
  __hip_bfloat16 h = __float2bfloat16(f);
  return *(short*)&h;
}

// Prepack: dst[(half,e,nt,kc,lane,j)] = src[(e*256 + nt*16 + (lane&15))*256
//                                           + kc*32 + (lane>>4)*8 + j]
// B-operand fragment layout for mfma_f32_16x16x32_bf16: n=lane&15, k=(lane>>4)*8+j.
// Thread mapping chosen so 32 consecutive threads read one contiguous 1KB
// source row (fully coalesced); the 16B fragment stores scatter instead.
__global__ __launch_bounds__(256) void prepack_kernel(
    const float* __restrict__ w1, const float* __restrict__ w2,
    __hip_bfloat16* __restrict__ dst)
{
  int o8   = blockIdx.x * 256 + threadIdx.x;  // 0 .. 65535 (8-elem chunks)
  int half = o8 >> 15;                        // 0: w1, 1: w2
  int idx  = o8 & 32767;
  int j    = idx & 31;                        // 8-float chunk within source row
  int rowid= idx >> 5;                        // e*256 + nt*16 + row, 0..1023
  int e    = rowid >> 8;
  int nt   = (rowid >> 4) & 15;
  int row  = rowid & 15;
  int kc   = j >> 2;
  int col8 = j & 3;
  int lane = (col8 << 4) | row;
  const float* src = half ? w2 : w1;
  const float* s = src + rowid * 256 + j * 8;
  const float4 v0 = *(const float4*)s;
  const float4 v1 = *(const float4*)(s + 4);
  bf16x8 outv = {bfq(v0.x), bfq(v0.y), bfq(v0.z), bfq(v0.w),
                 bfq(v1.x), bfq(v1.y), bfq(v1.z), bfq(v1.w)};
  int chunk = ((e*16 + nt)*8 + kc)*64 + lane;
  *(bf16x8*)((short*)dst + half*WFRAG_ELEMS + chunk*8) = outv;
}

// GEMM1 over MTC gathered M-tiles; barrier (protecting Hs readers of the
// previous expert's GEMM2) sits BETWEEN the MFMA loop and the H-scatter.
template<int MTC>
__device__ __forceinline__ void gemm1_sparse(
    const short* XsS, short* HsS, const short* w1e, const float* b1e,
    const unsigned char* plist_e, const float* wgtg_e,
    int wv, int r, int q, bool dosync)
{
  f32x4 hacc[MTC][2];
#pragma unroll
  for (int i = 0; i < MTC; ++i)
#pragma unroll
    for (int j = 0; j < 2; ++j) hacc[i][j] = (f32x4){0.f, 0.f, 0.f, 0.f};

  int aoff[MTC];
#pragma unroll
  for (int Mt = 0; Mt < MTC; ++Mt)
    aoff[Mt] = (int)plist_e[Mt*16 + r] * XST;

  bf16x8 bw[2][2];
#pragma unroll
  for (int t = 0; t < 2; ++t) bw[0][t] = *(const bf16x8*)(w1e + (t*8 + 0)*512);
#pragma unroll
  for (int kc = 0; kc < 8; ++kc) {
    if (kc < 7) {
#pragma unroll
      for (int t = 0; t < 2; ++t)
        bw[(kc+1)&1][t] = *(const bf16x8*)(w1e + (t*8 + kc + 1)*512);
    }
    bf16x8 a[MTC];
#pragma unroll
    for (int Mt = 0; Mt < MTC; ++Mt)
      a[Mt] = *(const bf16x8*)(XsS + aoff[Mt] + kc*32 + q*8);
#pragma unroll
    for (int Mt = 0; Mt < MTC; ++Mt)
#pragma unroll
      for (int t = 0; t < 2; ++t)
        hacc[Mt][t] = __builtin_amdgcn_mfma_f32_16x16x32_bf16(a[Mt], bw[kc&1][t], hacc[Mt][t], 0, 0, 0);
  }

  if (dosync) __syncthreads();   // prev expert's GEMM2 done reading Hs

  // epilogue: +b1, fast SiLU, scale by gathered gate weight, scatter to Hs
#pragma unroll
  for (int Mt = 0; Mt < MTC; ++Mt) {
    const int g0 = Mt*16 + q*4;
    const unsigned pw = *(const unsigned*)(plist_e + g0);   // 4 packed positions
    const f32x4 wg = *(const f32x4*)(wgtg_e + g0);
#pragma unroll
    for (int t = 0; t < 2; ++t) {
      const int n = wv*32 + t*16 + r;
      const float bias = b1e[n];
#pragma unroll
      for (int reg = 0; reg < 4; ++reg) {
        const int p = (pw >> (8*reg)) & 255;
        const float z = hacc[Mt][t][reg] + bias;
        const float s = __builtin_amdgcn_rcpf(1.0f + __expf(-z));
        HsS[p*XST + n] = bfq(z * s * wg[reg]);
      }
    }
  }
}

__global__ __launch_bounds__(512, 8) void moe_fused_kernel(
    const float* __restrict__ x,
    const float* __restrict__ gate_w,
    const float* __restrict__ gate_b,
    const float* __restrict__ b1,
    const float* __restrict__ b2,
    const __hip_bfloat16* __restrict__ wp,   // [W1P | W2P] prepacked bf16
    float* __restrict__ out)
{
  // pool (36864 B): phase 1 Xs (16896) + Hs (16896); epilogue O tile 256xOSTx4.
  // Gate fp64 partials (16KB) alias the Hs region before its first use.
  __shared__ __align__(16) char pool[256 * OST * 4];
  __shared__ __align__(16) float Wgt[MT * 4];
  __shared__ __align__(16) unsigned char plist[4][32];  // gathered positions
  __shared__ __align__(16) float WgtG[4][32];           // gathered gate weights
  __shared__ __align__(4)  unsigned char zlist[4][32];  // complement positions
  __shared__ int mcnt[4];

  short* XsS = (short*)pool;
  short* HsS = (short*)(pool + MT * XST * 2);
  float* Os  = (float*)pool;

  const int tid  = threadIdx.x;
  const int lane = tid & 63;
  const int wv   = tid >> 6;     // wave 0..7: owns n-slice [wv*32, wv*32+32)
  const int r    = lane & 15;
  const int q    = lane >> 4;

  const int g  = blockIdx.x;
  const int b  = g >> 9;                 // 512 workgroups per batch
  const int s0 = (g & 511) * MT;
  const float* xb = x + (size_t)b * C_DIM * S_DIM + s0;

  // ---- FUSED stage X + gate partials: wave wv owns channels [wv*32, wv*32+32),
  //      lane = p + 32*h: position p, channel-half h (16 ch each). Coalesced
  //      scalar loads; fp64 gate dot from the regs already holding x. ----
  {
    const int p  = lane & 31;
    const int h  = lane >> 5;
    const int c0 = wv * 32 + h * 16;
    float xv[16];
#pragma unroll
    for (int j = 0; j < 16; ++j)
      xv[j] = xb[(size_t)(c0 + j) * S_DIM + p];

    double acc[4] = {0.0, 0.0, 0.0, 0.0};
#pragma unroll
    for (int j = 0; j < 16; ++j) {
      const double xd = (double)xv[j];
      acc[0] += xd * (double)gate_w[0*256 + c0 + j];
      acc[1] += xd * (double)gate_w[1*256 + c0 + j];
      acc[2] += xd * (double)gate_w[2*256 + c0 + j];
      acc[3] += xd * (double)gate_w[3*256 + c0 + j];
    }

#pragma unroll
    for (int k = 0; k < 2; ++k) {
      bf16x8 blk = {bfq(xv[k*8+0]), bfq(xv[k*8+1]), bfq(xv[k*8+2]), bfq(xv[k*8+3]),
                    bfq(xv[k*8+4]), bfq(xv[k*8+5]), bfq(xv[k*8+6]), bfq(xv[k*8+7])};
      *(bf16x8*)(XsS + p*XST + c0 + k*8) = blk;
    }

    double* GateD = (double*)HsS;   // 32pos x 4e x 16grp fp64 = 16KB (alias)
#pragma unroll
    for (int e = 0; e < 4; ++e)
      GateD[(e*16 + wv*2 + h)*32 + p] = acc[e];
  }
  __syncthreads();   // Xs staged AND gate partials written

  // ---- logits (fp64 reduce, fixed order) + top-2 + softmax, fused via shfl ----
  if (tid < 128) {
    const int p = tid >> 2;
    const int e = tid & 3;
    const double* GateD = (const double*)HsS;
    double s = (double)gate_b[e];
#pragma unroll
    for (int g2 = 0; g2 < 16; ++g2) s += GateD[(e*16 + g2)*32 + p];
    const float la = (float)s;              // l[e]
    const float lb = __shfl_xor(la, 1, 64); // l[e^1]
    const float lc = __shfl_xor(la, 2, 64); // l[e^2]
    const float ld = __shfl_xor(lb, 2, 64); // l[e^3]
    if (e == 0) {
      const float l0 = la, l1 = lb, l2 = lc, l3 = ld;
      int i1 = 0; float v1 = l0;
      if (l1 > v1) { v1 = l1; i1 = 1; }
      if (l2 > v1) { v1 = l2; i1 = 2; }
      if (l3 > v1) { v1 = l3; i1 = 3; }
      float v2 = -3.0e38f; int i2 = 0;
      if (i1 != 0 && l0 > v2) { v2 = l0; i2 = 0; }
      if (i1 != 1 && l1 > v2) { v2 = l1; i2 = 1; }
      if (i1 != 2 && l2 > v2) { v2 = l2; i2 = 2; }
      if (i1 != 3 && l3 > v2) { v2 = l3; i2 = 3; }
      const float wA = 1.0f / (1.0f + __expf(v2 - v1));
      const float wB = 1.0f - wA;
      f32x4 w;
      w[0] = (i1 == 0) ? wA : ((i2 == 0) ? wB : 0.0f);
      w[1] = (i1 == 1) ? wA : ((i2 == 1) ? wB : 0.0f);
      w[2] = (i1 == 2) ? wA : ((i2 == 2) ? wB : 0.0f);
      w[3] = (i1 == 3) ? wA : ((i2 == 3) ? wB : 0.0f);
      *(f32x4*)(&Wgt[p*4]) = w;
    }
  }
  __syncthreads();   // Wgt final

  // ---- per-expert gather lists via ballot (waves 0..3, lanes 0..31 live) ----
  if (wv < 4) {
    const int e = wv;
    const int p = lane;
    const float w = (p < MT) ? Wgt[p*4 + e] : 0.0f;
    const bool sel = (w != 0.0f);
    const unsigned long long mask = __ballot(sel);
    const int below = __popcll(mask & ((1ull << p) - 1ull));
    const int m = __popcll(mask);
    const int pad = (((m + 15) >> 4) << 4) - m;
    if (p < MT) {
      if (sel) {
        plist[e][below] = (unsigned char)p;
        WgtG[e][below]  = w;
      } else {
        const int zidx = p - below;
        zlist[e][zidx] = (unsigned char)p;
        if (zidx < pad) {   // tail-tile padding: weight-0 complement rows
          plist[e][m + zidx] = (unsigned char)p;
          WgtG[e][m + zidx]  = 0.0f;
        }
      }
    }
    if (p == 0) mcnt[e] = m;
  }
  __syncthreads();   // lists final (also: GateD fully consumed before H-scatter)

  const short* W1P = (const short*)wp;
  const short* W2P = (const short*)wp + WFRAG_ELEMS;

  f32x4 oacc[2][2];   // [Mt][t]: persistent out accumulator, K=1024 concat
#pragma unroll
  for (int i = 0; i < 2; ++i)
#pragma unroll
    for (int j = 0; j < 2; ++j) oacc[i][j] = (f32x4){0.f, 0.f, 0.f, 0.f};

  for (int e = 0; e < E_DIM; ++e) {
    const int me = mcnt[e];   // WG-uniform
    const int mt = __builtin_amdgcn_readfirstlane((me + 15) >> 4);
    const short* w1e = W1P + ((e*16 + wv*2)*8)*512 + lane*8;
    const float* b1e = b1 + e*256;
    const bool dosync = (e > 0);   // wait for prev GEMM2's Hs readers

    if      (mt == 1) gemm1_sparse<1>(XsS, HsS, w1e, b1e, plist[e], WgtG[e], wv, r, q, dosync);
    else if (mt == 2) gemm1_sparse<2>(XsS, HsS, w1e, b1e, plist[e], WgtG[e], wv, r, q, dosync);
    else { if (dosync) __syncthreads(); }   // mt==0: still must sync

    // prefetch GEMM2's first kc B-fragments
    const short* w2e = W2P + ((e*16 + wv*2)*8)*512 + lane*8;
    bf16x8 cw[2][2];
#pragma unroll
    for (int t = 0; t < 2; ++t) cw[0][t] = *(const bf16x8*)(w2e + (t*8 + 0)*512);

    // zero-fill complement rows of Hs (positions not using expert e)
    {
      const int zm = MT - me;
      const bf16x8 zz = {0,0,0,0,0,0,0,0};
      for (int i = tid; i < zm*32; i += 512) {
        const int row = zlist[e][i >> 5];
        *(bf16x8*)(HsS + row*XST + (i & 31)*8) = zz;
      }
    }
    __syncthreads();   // Hs complete (gathered writes + zero fill)

    // ---- GEMM2: oacc += H_e(32x256) @ W2_e^T slice, ring-2 prefetch ----
    {
#pragma unroll
      for (int kc = 0; kc < 8; ++kc) {
        if (kc < 7) {
#pragma unroll
          for (int t = 0; t < 2; ++t)
            cw[(kc+1)&1][t] = *(const bf16x8*)(w2e + (t*8 + kc + 1)*512);
        }
        bf16x8 a[2];
#pragma unroll
        for (int Mt = 0; Mt < 2; ++Mt)
          a[Mt] = *(const bf16x8*)(HsS + (Mt*16 + r)*XST + kc*32 + q*8);
#pragma unroll
        for (int Mt = 0; Mt < 2; ++Mt)
#pragma unroll
          for (int t = 0; t < 2; ++t)
            oacc[Mt][t] = __builtin_amdgcn_mfma_f32_16x16x32_bf16(a[Mt], cw[kc&1][t], oacc[Mt][t], 0, 0, 0);
      }
    }
    // no barrier here: next expert's GEMM1 compute doesn't touch Hs; the
    // barrier protecting Hs sits inside gemm1_sparse, before its scatter.
  }
  __syncthreads();   // last GEMM2 done; pool may be reused as O tile

  // ---- O epilogue part 1: oacc + b2-wsum -> fp32 LDS O tile (b128 writes) ----
  {
    float b2v[2][4];   // [t][e] for c = wv*32 + t*16 + r
#pragma unroll
    for (int t = 0; t < 2; ++t) {
      const int c = wv*32 + t*16 + r;
#pragma unroll
      for (int e = 0; e < 4; ++e) b2v[t][e] = b2[e*256 + c];
    }
#pragma unroll
    for (int Mt = 0; Mt < 2; ++Mt) {
      f32x4 wv4[4];
#pragma unroll
      for (int reg = 0; reg < 4; ++reg)
        wv4[reg] = *(const f32x4*)(&Wgt[(Mt*16 + q*4 + reg)*4]);
#pragma unroll
      for (int t = 0; t < 2; ++t) {
        f32x4 v = oacc[Mt][t];
#pragma unroll
        for (int reg = 0; reg < 4; ++reg)
          v[reg] += wv4[reg][0]*b2v[t][0] + wv4[reg][1]*b2v[t][1]
                  + wv4[reg][2]*b2v[t][2] + wv4[reg][3]*b2v[t][3];
        *(f32x4*)(Os + (size_t)(wv*32 + t*16 + r)*OST + Mt*16 + q*4) = v;
      }
    }
  }
  __syncthreads();

  // ---- O epilogue part 2: coalesced residual-add + float4 store ----
  {
    const int p4 = (tid & 7) * 4;
    const int cg = tid >> 3;             // 0..63
    float* ob = out + (size_t)b * C_DIM * S_DIM + s0;
#pragma unroll
    for (int cc = 0; cc < 4; ++cc) {
      const int c = cc*64 + cg;
      const f32x4  o  = *(const f32x4*)(Os + (size_t)c*OST + p4);
      const float4 xr = *(const float4*)(xb + (size_t)c*S_DIM + p4);
      float4 res;
      res.x = o[0] + xr.x; res.y = o[1] + xr.y;
      res.z = o[2] + xr.z; res.w = o[3] + xr.w;
      *(float4*)(ob + (size_t)c*S_DIM + p4) = res;
    }
  }
}

extern "C" void kernel_launch(void* const* d_in, const int* in_sizes, int n_in,
                              void* d_out, int out_size, void* d_ws, size_t ws_size,
                              hipStream_t stream)
{
  (void)in_sizes; (void)n_in; (void)out_size; (void)ws_size;
  const float* x      = (const float*)d_in[0];
  const float* gate_w = (const float*)d_in[1];
  const float* gate_b = (const float*)d_in[2];
  const float* w1     = (const float*)d_in[3];
  const float* b1     = (const float*)d_in[4];
  const float* w2     = (const float*)d_in[5];
  const float* b2     = (const float*)d_in[6];
  float* out = (float*)d_out;
  __hip_bfloat16* wpack = (__hip_bfloat16*)d_ws;   // needs 1 MiB of scratch

  prepack_kernel<<<256, 256, 0, stream>>>(w1, w2, wpack);
  moe_fused_kernel<<<1024, 512, 0, stream>>>(x, gate_w, gate_b, b1, b2, wpack, out);
}

// Round 2
// 149.653 us; speedup vs baseline: 1.2085x; 1.2085x over previous
//
#include <hip/hip_runtime.h>
#include <hip/hip_bf16.h>

// MoE fused block, MI355X gfx950.
// Shapes: B=2, C=256, T*H*W=16384, E=4, K=2. All inputs fp32, output fp32.
//
// R8 -> R9:
//  * REVERT the MT=32 / launch_bounds(512,8) experiment: forcing 8 waves/EU
//    made the allocator target 32 arch-VGPRs and spill (WRITE_SIZE 33->188MB
//    of scratch). Back to MT=64, 512 WGs, launch_bounds(512,4) (128-VGPR cap,
//    2 WGs/CU) -- the R7 operating point (51.8us).
//  * Weight pipeline deepened: ring-4 fragment buffers with depth-3 prefetch
//    for BOTH GEMMs (was ring-2/depth-1). One kc of MFMA (~40cy) << L2
//    latency (~200-300cy); depth-3 keeps ~3 layers in flight.
//  * Expert-0 GEMM1 prologue (6 x 16B loads) hoisted BEFORE the staging
//    phase -- hidden under the 32 x-loads + fp64 gate chain. Per-expert
//    prologues (e>0) issue right after the previous GEMM2's MFMAs.
//  * GEMM2 prologue widened to 3 slots, still issued before zero-fill+barrier.
//  * Prepack keeps the R8 coalesced-read form (verified correct).

#define C_DIM 256
#define S_DIM 16384          // T*H*W
#define E_DIM 4
#define MT 64                // positions per workgroup
#define XST 264              // Xs/Hs row stride in shorts (16B-aligned rows)
#define OST 68               // O-tile row stride in floats (16B-aligned)
#define WFRAG_ELEMS 262144   // elements per prepacked weight tensor (4*16*8*64*8)

typedef __attribute__((ext_vector_type(8))) short bf16x8;
typedef __attribute__((ext_vector_type(4))) float f32x4;

__device__ __forceinline__ short bfq(float f) {
  __hip_bfloat16 h = __float2bfloat16(f);
  return *(short*)&h;
}

// Prepack: dst[(half,e,nt,kc,lane,j)] = src[(e*256 + nt*16 + (lane&15))*256
//                                           + kc*32 + (lane>>4)*8 + j]
// B-operand fragment layout for mfma_f32_16x16x32_bf16: n=lane&15, k=(lane>>4)*8+j.
// Thread mapping: 32 consecutive threads read one contiguous 1KB source row
// (fully coalesced); the 16B fragment stores scatter instead (fire-and-forget).
__global__ __launch_bounds__(256) void prepack_kernel(
    const float* __restrict__ w1, const float* __restrict__ w2,
    __hip_bfloat16* __restrict__ dst)
{
  int o8   = blockIdx.x * 256 + threadIdx.x;  // 0 .. 65535 (8-elem chunks)
  int half = o8 >> 15;                        // 0: w1, 1: w2
  int idx  = o8 & 32767;
  int j    = idx & 31;                        // 8-float chunk within source row
  int rowid= idx >> 5;                        // e*256 + nt*16 + row, 0..1023
  int e    = rowid >> 8;
  int nt   = (rowid >> 4) & 15;
  int row  = rowid & 15;
  int kc   = j >> 2;
  int col8 = j & 3;
  int lane = (col8 << 4) | row;
  const float* src = half ? w2 : w1;
  const float* s = src + rowid * 256 + j * 8;
  const float4 v0 = *(const float4*)s;
  const float4 v1 = *(const float4*)(s + 4);
  bf16x8 outv = {bfq(v0.x), bfq(v0.y), bfq(v0.z), bfq(v0.w),
                 bfq(v1.x), bfq(v1.y), bfq(v1.z), bfq(v1.w)};
  int chunk = ((e*16 + nt)*8 + kc)*64 + lane;
  *(bf16x8*)((short*)dst + half*WFRAG_ELEMS + chunk*8) = outv;
}

// GEMM1 over MTC gathered M-tiles; barrier (protecting Hs readers of the
// previous expert's GEMM2) sits BETWEEN the MFMA loop and the H-scatter.
// bw[] arrives with slots 0..2 preloaded (depth-3 prologue issued by caller,
// overlapped with staging (e==0) or the previous GEMM2 (e>0)).
template<int MTC>
__device__ __forceinline__ void gemm1_sparse(
    const short* XsS, short* HsS, const short* w1e, const float* b1e,
    const unsigned char* plist_e, const float* wgtg_e,
    bf16x8 (&bw)[4][2],
    int wv, int r, int q, bool dosync)
{
  f32x4 hacc[MTC][2];
#pragma unroll
  for (int i = 0; i < MTC; ++i)
#pragma unroll
    for (int j = 0; j < 2; ++j) hacc[i][j] = (f32x4){0.f, 0.f, 0.f, 0.f};

  int aoff[MTC];
#pragma unroll
  for (int Mt = 0; Mt < MTC; ++Mt)
    aoff[Mt] = (int)plist_e[Mt*16 + r] * XST;

#pragma unroll
  for (int kc = 0; kc < 8; ++kc) {
    if (kc < 5) {   // depth-3 ring prefetch
#pragma unroll
      for (int t = 0; t < 2; ++t)
        bw[(kc+3)&3][t] = *(const bf16x8*)(w1e + (t*8 + kc + 3)*512);
    }
    bf16x8 a[MTC];
#pragma unroll
    for (int Mt = 0; Mt < MTC; ++Mt)
      a[Mt] = *(const bf16x8*)(XsS + aoff[Mt] + kc*32 + q*8);
#pragma unroll
    for (int Mt = 0; Mt < MTC; ++Mt)
#pragma unroll
      for (int t = 0; t < 2; ++t)
        hacc[Mt][t] = __builtin_amdgcn_mfma_f32_16x16x32_bf16(a[Mt], bw[kc&3][t], hacc[Mt][t], 0, 0, 0);
  }

  if (dosync) __syncthreads();   // prev expert's GEMM2 done reading Hs

  // epilogue: +b1, fast SiLU, scale by gathered gate weight, scatter to Hs
#pragma unroll
  for (int Mt = 0; Mt < MTC; ++Mt) {
    const int g0 = Mt*16 + q*4;
    const unsigned pw = *(const unsigned*)(plist_e + g0);   // 4 packed positions
    const f32x4 wg = *(const f32x4*)(wgtg_e + g0);
#pragma unroll
    for (int t = 0; t < 2; ++t) {
      const int n = wv*32 + t*16 + r;
      const float bias = b1e[n];
#pragma unroll
      for (int reg = 0; reg < 4; ++reg) {
        const int p = (pw >> (8*reg)) & 255;
        const float z = hacc[Mt][t][reg] + bias;
        const float s = __builtin_amdgcn_rcpf(1.0f + __expf(-z));
        HsS[p*XST + n] = bfq(z * s * wg[reg]);
      }
    }
  }
}

__global__ __launch_bounds__(512, 4) void moe_fused_kernel(
    const float* __restrict__ x,
    const float* __restrict__ gate_w,
    const float* __restrict__ gate_b,
    const float* __restrict__ b1,
    const float* __restrict__ b2,
    const __hip_bfloat16* __restrict__ wp,   // [W1P | W2P] prepacked bf16
    float* __restrict__ out)
{
  // pool (69632 B): phase 1 Xs (33792) + Hs (33792); epilogue O tile 256xOSTx4.
  // Gate fp64 partials (16KB) alias the Hs region before its first use.
  __shared__ __align__(16) char pool[256 * OST * 4];
  __shared__ __align__(16) float Wgt[MT * 4];
  __shared__ __align__(16) unsigned char plist[4][64];  // gathered positions
  __shared__ __align__(16) float WgtG[4][64];           // gathered gate weights
  __shared__ __align__(4)  unsigned char zlist[4][64];  // complement positions
  __shared__ int mcnt[4];

  short* XsS = (short*)pool;
  short* HsS = (short*)(pool + MT * XST * 2);
  float* Os  = (float*)pool;

  const int tid  = threadIdx.x;
  const int lane = tid & 63;
  const int wv   = tid >> 6;     // wave 0..7: owns n-slice [wv*32, wv*32+32)
  const int r    = lane & 15;
  const int q    = lane >> 4;

  const int g  = blockIdx.x;
  const int b  = g >> 8;                 // 256 workgroups per batch
  const int s0 = (g & 255) * MT;
  const float* xb = x + (size_t)b * C_DIM * S_DIM + s0;

  const short* W1P = (const short*)wp;
  const short* W2P = (const short*)wp + WFRAG_ELEMS;

  // ---- expert-0 GEMM1 prologue: issue NOW, consume after the barriers.
  //      Latency hides under the whole staging + gate phase. ----
  bf16x8 bw[4][2];
  {
    const short* w10 = W1P + ((0*16 + wv*2)*8)*512 + lane*8;
#pragma unroll
    for (int kk = 0; kk < 3; ++kk)
#pragma unroll
      for (int t = 0; t < 2; ++t)
        bw[kk][t] = *(const bf16x8*)(w10 + (t*8 + kk)*512);
  }

  // ---- FUSED stage X + gate partials: wave wv owns channels [wv*32, wv*32+32),
  //      lane = position. 32 coalesced scalar loads; fp64 gate dot from regs. ----
  {
    const int p  = lane;
    const int c0 = wv * 32;
    float xv[32];
#pragma unroll
    for (int j = 0; j < 32; ++j)
      xv[j] = xb[(size_t)(c0 + j) * S_DIM + p];

    double acc[4] = {0.0, 0.0, 0.0, 0.0};
#pragma unroll
    for (int j = 0; j < 32; ++j) {
      const double xd = (double)xv[j];
      acc[0] += xd * (double)gate_w[0*256 + c0 + j];
      acc[1] += xd * (double)gate_w[1*256 + c0 + j];
      acc[2] += xd * (double)gate_w[2*256 + c0 + j];
      acc[3] += xd * (double)gate_w[3*256 + c0 + j];
    }

#pragma unroll
    for (int k = 0; k < 4; ++k) {
      bf16x8 blk = {bfq(xv[k*8+0]), bfq(xv[k*8+1]), bfq(xv[k*8+2]), bfq(xv[k*8+3]),
                    bfq(xv[k*8+4]), bfq(xv[k*8+5]), bfq(xv[k*8+6]), bfq(xv[k*8+7])};
      *(bf16x8*)(XsS + p*XST + c0 + k*8) = blk;
    }

    double* GateD = (double*)HsS;   // 64pos x 4e x 8grp fp64 = 16KB (alias)
#pragma unroll
    for (int e = 0; e < 4; ++e)
      GateD[(e*8 + wv)*64 + p] = acc[e];
  }
  __syncthreads();   // Xs staged AND gate partials written

  // ---- logits (fp64 reduce, fixed order) + top-2 + softmax, fused via shfl ----
  if (tid < 256) {
    const int p = tid >> 2;
    const int e = tid & 3;
    const double* GateD = (const double*)HsS;
    double s = (double)gate_b[e];
#pragma unroll
    for (int g2 = 0; g2 < 8; ++g2) s += GateD[(e*8 + g2)*64 + p];
    const float la = (float)s;              // l[e]
    const float lb = __shfl_xor(la, 1, 64); // l[e^1]
    const float lc = __shfl_xor(la, 2, 64); // l[e^2]
    const float ld = __shfl_xor(lb, 2, 64); // l[e^3]
    if (e == 0) {
      const float l0 = la, l1 = lb, l2 = lc, l3 = ld;
      int i1 = 0; float v1 = l0;
      if (l1 > v1) { v1 = l1; i1 = 1; }
      if (l2 > v1) { v1 = l2; i1 = 2; }
      if (l3 > v1) { v1 = l3; i1 = 3; }
      float v2 = -3.0e38f; int i2 = 0;
      if (i1 != 0 && l0 > v2) { v2 = l0; i2 = 0; }
      if (i1 != 1 && l1 > v2) { v2 = l1; i2 = 1; }
      if (i1 != 2 && l2 > v2) { v2 = l2; i2 = 2; }
      if (i1 != 3 && l3 > v2) { v2 = l3; i2 = 3; }
      const float wA = 1.0f / (1.0f + __expf(v2 - v1));
      const float wB = 1.0f - wA;
      f32x4 w;
      w[0] = (i1 == 0) ? wA : ((i2 == 0) ? wB : 0.0f);
      w[1] = (i1 == 1) ? wA : ((i2 == 1) ? wB : 0.0f);
      w[2] = (i1 == 2) ? wA : ((i2 == 2) ? wB : 0.0f);
      w[3] = (i1 == 3) ? wA : ((i2 == 3) ? wB : 0.0f);
      *(f32x4*)(&Wgt[p*4]) = w;
    }
  }
  __syncthreads();   // Wgt final

  // ---- per-expert gather lists via ballot (waves 0..3) ----
  if (wv < 4) {
    const int e = wv;
    const int p = lane;
    const float w = Wgt[p*4 + e];
    const bool sel = (w != 0.0f);
    const unsigned long long mask = __ballot(sel);
    const int below = __popcll(mask & ((1ull << p) - 1ull));
    const int m = __popcll(mask);
    const int pad = (((m + 15) >> 4) << 4) - m;
    if (sel) {
      plist[e][below] = (unsigned char)p;
      WgtG[e][below]  = w;
    } else {
      const int zidx = p - below;
      zlist[e][zidx] = (unsigned char)p;
      if (zidx < pad) {   // tail-tile padding: weight-0 complement rows
        plist[e][m + zidx] = (unsigned char)p;
        WgtG[e][m + zidx]  = 0.0f;
      }
    }
    if (p == 0) mcnt[e] = m;
  }
  __syncthreads();   // lists final (also: GateD fully consumed before H-scatter)

  f32x4 oacc[4][2];   // [Mt][t]: persistent out accumulator, K=1024 concat
#pragma unroll
  for (int i = 0; i < 4; ++i)
#pragma unroll
    for (int j = 0; j < 2; ++j) oacc[i][j] = (f32x4){0.f, 0.f, 0.f, 0.f};

  for (int e = 0; e < E_DIM; ++e) {
    const int me = mcnt[e];   // WG-uniform
    const int mt = __builtin_amdgcn_readfirstlane((me + 15) >> 4);
    const short* w1e = W1P + ((e*16 + wv*2)*8)*512 + lane*8;
    const float* b1e = b1 + e*256;
    const bool dosync = (e > 0);   // wait for prev GEMM2's Hs readers

    if (e > 0) {   // prologue for this expert's GEMM1: overlap prev GEMM2 tail
#pragma unroll
      for (int kk = 0; kk < 3; ++kk)
#pragma unroll
        for (int t = 0; t < 2; ++t)
          bw[kk][t] = *(const bf16x8*)(w1e + (t*8 + kk)*512);
    }

    if      (mt == 2) gemm1_sparse<2>(XsS, HsS, w1e, b1e, plist[e], WgtG[e], bw, wv, r, q, dosync);
    else if (mt == 3) gemm1_sparse<3>(XsS, HsS, w1e, b1e, plist[e], WgtG[e], bw, wv, r, q, dosync);
    else if (mt == 4) gemm1_sparse<4>(XsS, HsS, w1e, b1e, plist[e], WgtG[e], bw, wv, r, q, dosync);
    else if (mt == 1) gemm1_sparse<1>(XsS, HsS, w1e, b1e, plist[e], WgtG[e], bw, wv, r, q, dosync);
    else { if (dosync) __syncthreads(); }   // mt==0: still must sync

    // GEMM2 prologue (3 slots): issue before zero-fill + barrier
    const short* w2e = W2P + ((e*16 + wv*2)*8)*512 + lane*8;
    bf16x8 cw[4][2];
#pragma unroll
    for (int kk = 0; kk < 3; ++kk)
#pragma unroll
      for (int t = 0; t < 2; ++t)
        cw[kk][t] = *(const bf16x8*)(w2e + (t*8 + kk)*512);

    // zero-fill complement rows of Hs (positions not using expert e)
    {
      const int zm = MT - me;
      const bf16x8 zz = {0,0,0,0,0,0,0,0};
      for (int i = tid; i < zm*32; i += 512) {
        const int row = zlist[e][i >> 5];
        *(bf16x8*)(HsS + row*XST + (i & 31)*8) = zz;
      }
    }
    __syncthreads();   // Hs complete (gathered writes + zero fill)

    // ---- GEMM2: oacc += H_e(64x256) @ W2_e^T slice, depth-3 ring prefetch ----
    {
#pragma unroll
      for (int kc = 0; kc < 8; ++kc) {
        if (kc < 5) {
#pragma unroll
          for (int t = 0; t < 2; ++t)
            cw[(kc+3)&3][t] = *(const bf16x8*)(w2e + (t*8 + kc + 3)*512);
        }
        bf16x8 a[4];
#pragma unroll
        for (int Mt = 0; Mt < 4; ++Mt)
          a[Mt] = *(const bf16x8*)(HsS + (Mt*16 + r)*XST + kc*32 + q*8);
#pragma unroll
        for (int Mt = 0; Mt < 4; ++Mt)
#pragma unroll
          for (int t = 0; t < 2; ++t)
            oacc[Mt][t] = __builtin_amdgcn_mfma_f32_16x16x32_bf16(a[Mt], cw[kc&1 ? (kc&3) : (kc&3)][t], oacc[Mt][t], 0, 0, 0);
      }
    }
    // no barrier here: next expert's GEMM1 compute doesn't touch Hs; the
    // barrier protecting Hs sits inside gemm1_sparse, before its scatter.
  }
  __syncthreads();   // last GEMM2 done; pool may be reused as O tile

  // ---- O epilogue part 1: oacc + b2-wsum -> fp32 LDS O tile (b128 writes) ----
  {
    float b2v[2][4];   // [t][e] for c = wv*32 + t*16 + r
#pragma unroll
    for (int t = 0; t < 2; ++t) {
      const int c = wv*32 + t*16 + r;
#pragma unroll
      for (int e = 0; e < 4; ++e) b2v[t][e] = b2[e*256 + c];
    }
#pragma unroll
    for (int Mt = 0; Mt < 4; ++Mt) {
      f32x4 wv4[4];
#pragma unroll
      for (int reg = 0; reg < 4; ++reg)
        wv4[reg] = *(const f32x4*)(&Wgt[(Mt*16 + q*4 + reg)*4]);
#pragma unroll
      for (int t = 0; t < 2; ++t) {
        f32x4 v = oacc[Mt][t];
#pragma unroll
        for (int reg = 0; reg < 4; ++reg)
          v[reg] += wv4[reg][0]*b2v[t][0] + wv4[reg][1]*b2v[t][1]
                  + wv4[reg][2]*b2v[t][2] + wv4[reg][3]*b2v[t][3];
        *(f32x4*)(Os + (size_t)(wv*32 + t*16 + r)*OST + Mt*16 + q*4) = v;
      }
    }
  }
  __syncthreads();

  // ---- O epilogue part 2: coalesced residual-add + float4 store ----
  {
    const int p4 = (tid & 15) * 4;
    const int cg = tid >> 4;             // 0..31
    float* ob = out + (size_t)b * C_DIM * S_DIM + s0;
#pragma unroll
    for (int cc = 0; cc < 8; ++cc) {
      const int c = cc*32 + cg;
      const f32x4  o  = *(const f32x4*)(Os + (size_t)c*OST + p4);
      const float4 xr = *(const float4*)(xb + (size_t)c*S_DIM + p4);
      float4 res;
      res.x = o[0] + xr.x; res.y = o[1] + xr.y;
      res.z = o[2] + xr.z; res.w = o[3] + xr.w;
      *(float4*)(ob + (size_t)c*S_DIM + p4) = res;
    }
  }
}

extern "C" void kernel_launch(void* const* d_in, const int* in_sizes, int n_in,
                              void* d_out, int out_size, void* d_ws, size_t ws_size,
                              hipStream_t stream)
{
  (void)in_sizes; (void)n_in; (void)out_size; (void)ws_size;
  const float* x      = (const float*)d_in[0];
  const float* gate_w = (const float*)d_in[1];
  const float* gate_b = (const float*)d_in[2];
  const float* w1     = (const float*)d_in[3];
  const float* b1     = (const float*)d_in[4];
  const float* w2     = (const float*)d_in[5];
  const float* b2     = (const float*)d_in[6];
  float* out = (float*)d_out;
  __hip_bfloat16* wpack = (__hip_bfloat16*)d_ws;   // needs 1 MiB of scratch

  prepack_kernel<<<256, 256, 0, stream>>>(w1, w2, wpack);
  moe_fused_kernel<<<512, 512, 0, stream>>>(x, gate_w, gate_b, b1, b2, wpack, out);
}

// Round 4
// 131.051 us; speedup vs baseline: 1.3800x; 1.1419x over previous
//
#include <hip/hip_runtime.h>
#include <hip/hip_bf16.h>

// MoE fused block, MI355X gfx950.
// Shapes: B=2, C=256, T*H*W=16384, E=4, K=2. All inputs fp32, output fp32.
//
// R10 resubmit (round-3 run died to a container/infra failure, not a kernel
// error; audit found no deadlock/OOB — barriers all WG-uniform, indices
// bounded, LDS 141.5KB < 160KB, reg structure == non-spilling R7):
//  * MT 64 -> 128 with 1024-thread WGs, 256 WGs = 1 WG/CU (16 waves/CU, same
//    as R7's 2x512). Halves per-CU L2 weight streaming (2MB -> 1MB): the two
//    M-half waves (mh=0/1) share each weight fragment via L1 instead of two
//    independent WGs re-pulling from L2. Grid == CU count: no tail.
//  * O epilogue: direct float4 global stores from oacc (MFMA D-layout gives 4
//    consecutive positions per lane) + residual float4 loads. Kills the fp32
//    LDS O-tile round trip and 2 barriers; LDS = Xs+Hs only (135KB).
//  * Per-expert gather: one wave per expert, two sequential 64-pos ballots.
//    Padding to 32*mt2 rows so the two mh waves split tiles evenly.

#define C_DIM 256
#define S_DIM 16384          // T*H*W
#define E_DIM 4
#define MT 128               // positions per workgroup
#define XST 264              // Xs/Hs row stride in shorts (16B-aligned rows)
#define WFRAG_ELEMS 262144   // elements per prepacked weight tensor (4*16*8*64*8)

typedef __attribute__((ext_vector_type(8))) short bf16x8;
typedef __attribute__((ext_vector_type(4))) float f32x4;

__device__ __forceinline__ short bfq(float f) {
  __hip_bfloat16 h = __float2bfloat16(f);
  return *(short*)&h;
}

// Prepack: dst[(half,e,nt,kc,lane,j)] = src[(e*256 + nt*16 + (lane&15))*256
//                                           + kc*32 + (lane>>4)*8 + j]
// B-operand fragment layout for mfma_f32_16x16x32_bf16: n=lane&15, k=(lane>>4)*8+j.
// 32 consecutive threads read one contiguous 1KB source row (fully coalesced);
// the 16B fragment stores scatter (fire-and-forget).
__global__ __launch_bounds__(256) void prepack_kernel(
    const float* __restrict__ w1, const float* __restrict__ w2,
    __hip_bfloat16* __restrict__ dst)
{
  int o8   = blockIdx.x * 256 + threadIdx.x;  // 0 .. 65535 (8-elem chunks)
  int half = o8 >> 15;                        // 0: w1, 1: w2
  int idx  = o8 & 32767;
  int j    = idx & 31;                        // 8-float chunk within source row
  int rowid= idx >> 5;                        // e*256 + nt*16 + row, 0..1023
  int e    = rowid >> 8;
  int nt   = (rowid >> 4) & 15;
  int row  = rowid & 15;
  int kc   = j >> 2;
  int col8 = j & 3;
  int lane = (col8 << 4) | row;
  const float* src = half ? w2 : w1;
  const float* s = src + rowid * 256 + j * 8;
  const float4 v0 = *(const float4*)s;
  const float4 v1 = *(const float4*)(s + 4);
  bf16x8 outv = {bfq(v0.x), bfq(v0.y), bfq(v0.z), bfq(v0.w),
                 bfq(v1.x), bfq(v1.y), bfq(v1.z), bfq(v1.w)};
  int chunk = ((e*16 + nt)*8 + kc)*64 + lane;
  *(bf16x8*)((short*)dst + half*WFRAG_ELEMS + chunk*8) = outv;
}

// GEMM1 over MTC gathered M-tiles (plist/wgtg already offset to this wave's
// tile range); barrier (protecting Hs readers of the previous expert's GEMM2)
// sits BETWEEN the MFMA loop and the H-scatter. Ring-2 weight prefetch (R7).
template<int MTC>
__device__ __forceinline__ void gemm1_sparse(
    const short* XsS, short* HsS, const short* w1e, const float* b1e,
    const unsigned char* plist_e, const float* wgtg_e,
    int nv, int r, int q, bool dosync)
{
  f32x4 hacc[MTC][2];
#pragma unroll
  for (int i = 0; i < MTC; ++i)
#pragma unroll
    for (int j = 0; j < 2; ++j) hacc[i][j] = (f32x4){0.f, 0.f, 0.f, 0.f};

  int aoff[MTC];
#pragma unroll
  for (int Mt = 0; Mt < MTC; ++Mt)
    aoff[Mt] = (int)plist_e[Mt*16 + r] * XST;

  bf16x8 bw[2][2];
#pragma unroll
  for (int t = 0; t < 2; ++t) bw[0][t] = *(const bf16x8*)(w1e + (t*8 + 0)*512);
#pragma unroll
  for (int kc = 0; kc < 8; ++kc) {
    if (kc < 7) {
#pragma unroll
      for (int t = 0; t < 2; ++t)
        bw[(kc+1)&1][t] = *(const bf16x8*)(w1e + (t*8 + kc + 1)*512);
    }
    bf16x8 a[MTC];
#pragma unroll
    for (int Mt = 0; Mt < MTC; ++Mt)
      a[Mt] = *(const bf16x8*)(XsS + aoff[Mt] + kc*32 + q*8);
#pragma unroll
    for (int Mt = 0; Mt < MTC; ++Mt)
#pragma unroll
      for (int t = 0; t < 2; ++t)
        hacc[Mt][t] = __builtin_amdgcn_mfma_f32_16x16x32_bf16(a[Mt], bw[kc&1][t], hacc[Mt][t], 0, 0, 0);
  }

  if (dosync) __syncthreads();   // prev expert's GEMM2 done reading Hs

  // epilogue: +b1, fast SiLU, scale by gathered gate weight, scatter to Hs
#pragma unroll
  for (int Mt = 0; Mt < MTC; ++Mt) {
    const int g0 = Mt*16 + q*4;
    const unsigned pw = *(const unsigned*)(plist_e + g0);   // 4 packed positions
    const f32x4 wg = *(const f32x4*)(wgtg_e + g0);
#pragma unroll
    for (int t = 0; t < 2; ++t) {
      const int n = nv*32 + t*16 + r;
      const float bias = b1e[n];
#pragma unroll
      for (int reg = 0; reg < 4; ++reg) {
        const int p = (pw >> (8*reg)) & 255;
        const float z = hacc[Mt][t][reg] + bias;
        const float s = __builtin_amdgcn_rcpf(1.0f + __expf(-z));
        HsS[p*XST + n] = bfq(z * s * wg[reg]);
      }
    }
  }
}

__global__ __launch_bounds__(1024, 4) void moe_fused_kernel(
    const float* __restrict__ x,
    const float* __restrict__ gate_w,
    const float* __restrict__ gate_b,
    const float* __restrict__ b1,
    const float* __restrict__ b2,
    const __hip_bfloat16* __restrict__ wp,   // [W1P | W2P] prepacked bf16
    float* __restrict__ out)
{
  // pool (135168 B): Xs (67584) + Hs (67584).
  // Gate fp64 partials (32KB) alias the Hs region before its first use.
  __shared__ __align__(16) char pool[2 * MT * XST * 2];
  __shared__ __align__(16) float Wgt[MT * 4];
  __shared__ __align__(16) unsigned char plist[4][192];  // gathered + pad positions
  __shared__ __align__(16) float WgtG[4][192];           // gathered gate weights
  __shared__ __align__(4)  unsigned char zlist[4][128];  // complement positions
  __shared__ int mcnt[4];

  short* XsS = (short*)pool;
  short* HsS = (short*)(pool + MT * XST * 2);

  const int tid  = threadIdx.x;
  const int lane = tid & 63;
  const int wv   = tid >> 6;     // wave 0..15
  const int nv   = wv & 7;       // n-slice owner: channels [nv*32, nv*32+32)
  const int mh   = wv >> 3;      // M-half: positions [mh*64, mh*64+64)
  const int r    = lane & 15;
  const int q    = lane >> 4;

  const int g  = blockIdx.x;
  const int b  = g >> 7;                 // 128 workgroups per batch
  const int s0 = (g & 127) * MT;
  const float* xb = x + (size_t)b * C_DIM * S_DIM + s0;

  const short* W1P = (const short*)wp;
  const short* W2P = (const short*)wp + WFRAG_ELEMS;

  // ---- FUSED stage X + gate partials: wave (nv,mh) owns channels
  //      [nv*32, nv*32+32) x positions [mh*64, mh*64+64); lane = position.
  //      32 coalesced scalar loads; fp64 gate dot from the regs holding x. ----
  {
    const int p  = mh*64 + lane;
    const int c0 = nv * 32;
    float xv[32];
#pragma unroll
    for (int j = 0; j < 32; ++j)
      xv[j] = xb[(size_t)(c0 + j) * S_DIM + p];

    double acc[4] = {0.0, 0.0, 0.0, 0.0};
#pragma unroll
    for (int j = 0; j < 32; ++j) {
      const double xd = (double)xv[j];
      acc[0] += xd * (double)gate_w[0*256 + c0 + j];
      acc[1] += xd * (double)gate_w[1*256 + c0 + j];
      acc[2] += xd * (double)gate_w[2*256 + c0 + j];
      acc[3] += xd * (double)gate_w[3*256 + c0 + j];
    }

#pragma unroll
    for (int k = 0; k < 4; ++k) {
      bf16x8 blk = {bfq(xv[k*8+0]), bfq(xv[k*8+1]), bfq(xv[k*8+2]), bfq(xv[k*8+3]),
                    bfq(xv[k*8+4]), bfq(xv[k*8+5]), bfq(xv[k*8+6]), bfq(xv[k*8+7])};
      *(bf16x8*)(XsS + p*XST + c0 + k*8) = blk;
    }

    double* GateD = (double*)HsS;   // 4e x 8grp x 128pos fp64 = 32KB (alias)
#pragma unroll
    for (int e = 0; e < 4; ++e)
      GateD[(e*8 + nv)*128 + p] = acc[e];
  }
  __syncthreads();   // Xs staged AND gate partials written

  // ---- logits (fp64 reduce, fixed order) + top-2 + softmax, fused via shfl ----
  if (tid < 512) {
    const int p = tid >> 2;        // 0..127
    const int e = tid & 3;
    const double* GateD = (const double*)HsS;
    double s = (double)gate_b[e];
#pragma unroll
    for (int g2 = 0; g2 < 8; ++g2) s += GateD[(e*8 + g2)*128 + p];
    const float la = (float)s;              // l[e]
    const float lb = __shfl_xor(la, 1, 64); // l[e^1]
    const float lc = __shfl_xor(la, 2, 64); // l[e^2]
    const float ld = __shfl_xor(lb, 2, 64); // l[e^3]
    if (e == 0) {
      const float l0 = la, l1 = lb, l2 = lc, l3 = ld;
      int i1 = 0; float v1 = l0;
      if (l1 > v1) { v1 = l1; i1 = 1; }
      if (l2 > v1) { v1 = l2; i1 = 2; }
      if (l3 > v1) { v1 = l3; i1 = 3; }
      float v2 = -3.0e38f; int i2 = 0;
      if (i1 != 0 && l0 > v2) { v2 = l0; i2 = 0; }
      if (i1 != 1 && l1 > v2) { v2 = l1; i2 = 1; }
      if (i1 != 2 && l2 > v2) { v2 = l2; i2 = 2; }
      if (i1 != 3 && l3 > v2) { v2 = l3; i2 = 3; }
      const float wA = 1.0f / (1.0f + __expf(v2 - v1));
      const float wB = 1.0f - wA;
      f32x4 w;
      w[0] = (i1 == 0) ? wA : ((i2 == 0) ? wB : 0.0f);
      w[1] = (i1 == 1) ? wA : ((i2 == 1) ? wB : 0.0f);
      w[2] = (i1 == 2) ? wA : ((i2 == 2) ? wB : 0.0f);
      w[3] = (i1 == 3) ? wA : ((i2 == 3) ? wB : 0.0f);
      *(f32x4*)(&Wgt[p*4]) = w;
    }
  }
  __syncthreads();   // Wgt final

  // ---- per-expert gather lists: wave e, two sequential 64-pos ballots ----
  if (wv < 4) {
    const int e = wv;
    int base = 0, zbase = 0;
#pragma unroll
    for (int half = 0; half < 2; ++half) {
      const int p = half*64 + lane;
      const float w = Wgt[p*4 + e];
      const bool sel = (w != 0.0f);
      const unsigned long long mask = __ballot(sel);
      const int below = __popcll(mask & ((1ull << lane) - 1ull));
      const int m = __popcll(mask);
      if (sel) {
        plist[e][base + below] = (unsigned char)p;
        WgtG[e][base + below]  = w;
      } else {
        zlist[e][zbase + lane - below] = (unsigned char)p;
      }
      base += m; zbase += 64 - m;
    }
    const int me  = base;
    const int mt2 = (me + 31) >> 5;          // tiles per mh-wave
    const int pad = mt2*32 - me;             // <= 31, and <= 128-me
    if (lane < pad) {                        // weight-0 complement padding rows
      plist[e][me + lane] = zlist[e][lane];
      WgtG[e][me + lane]  = 0.0f;
    }
    if (lane == 0) mcnt[e] = me;
  }
  __syncthreads();   // lists final (GateD fully consumed before H-scatter)

  f32x4 oacc[4][2];   // [Mt][t]: persistent out accumulator, K=1024 concat
#pragma unroll
  for (int i = 0; i < 4; ++i)
#pragma unroll
    for (int j = 0; j < 2; ++j) oacc[i][j] = (f32x4){0.f, 0.f, 0.f, 0.f};

  for (int e = 0; e < E_DIM; ++e) {
    const int me  = mcnt[e];   // WG-uniform
    const int mt2 = __builtin_amdgcn_readfirstlane((me + 31) >> 5);
    const short* w1e = W1P + ((e*16 + nv*2)*8)*512 + lane*8;
    const float* b1e = b1 + e*256;
    const unsigned char* pl = plist[e] + mh*mt2*16;   // this wave's tile range
    const float*         wg = WgtG[e]  + mh*mt2*16;
    const bool dosync = (e > 0);   // wait for prev GEMM2's Hs readers

    if      (mt2 == 2) gemm1_sparse<2>(XsS, HsS, w1e, b1e, pl, wg, nv, r, q, dosync);
    else if (mt2 == 1) gemm1_sparse<1>(XsS, HsS, w1e, b1e, pl, wg, nv, r, q, dosync);
    else if (mt2 == 3) gemm1_sparse<3>(XsS, HsS, w1e, b1e, pl, wg, nv, r, q, dosync);
    else if (mt2 == 4) gemm1_sparse<4>(XsS, HsS, w1e, b1e, pl, wg, nv, r, q, dosync);
    else { if (dosync) __syncthreads(); }   // mt2==0: still must sync

    // GEMM2 prologue: first kc B-fragments, issued before zero-fill + barrier
    const short* w2e = W2P + ((e*16 + nv*2)*8)*512 + lane*8;
    bf16x8 cw[2][2];
#pragma unroll
    for (int t = 0; t < 2; ++t) cw[0][t] = *(const bf16x8*)(w2e + (t*8 + 0)*512);

    // zero-fill complement rows of Hs (positions not using expert e)
    {
      const int zm = MT - me;
      const bf16x8 zz = {0,0,0,0,0,0,0,0};
      for (int i = tid; i < zm*32; i += 1024) {
        const int row = zlist[e][i >> 5];
        *(bf16x8*)(HsS + row*XST + (i & 31)*8) = zz;
      }
    }
    __syncthreads();   // Hs complete (gathered writes + zero fill)

    // ---- GEMM2: oacc += H_e(128x256) @ W2_e^T slice; this wave's 64 rows ----
    {
#pragma unroll
      for (int kc = 0; kc < 8; ++kc) {
        if (kc < 7) {
#pragma unroll
          for (int t = 0; t < 2; ++t)
            cw[(kc+1)&1][t] = *(const bf16x8*)(w2e + (t*8 + kc + 1)*512);
        }
        bf16x8 a[4];
#pragma unroll
        for (int Mt = 0; Mt < 4; ++Mt)
          a[Mt] = *(const bf16x8*)(HsS + (mh*64 + Mt*16 + r)*XST + kc*32 + q*8);
#pragma unroll
        for (int Mt = 0; Mt < 4; ++Mt)
#pragma unroll
          for (int t = 0; t < 2; ++t)
            oacc[Mt][t] = __builtin_amdgcn_mfma_f32_16x16x32_bf16(a[Mt], cw[kc&1][t], oacc[Mt][t], 0, 0, 0);
      }
    }
    // no barrier here: next expert's GEMM1 compute doesn't touch Hs; the
    // barrier protecting Hs sits inside gemm1_sparse, before its scatter.
  }

  // ---- O epilogue: direct stores. Lane holds 4 CONSECUTIVE positions per
  //      fragment (D-layout row = q*4+reg), so float4 res/store per (Mt,t).
  //      Reads Wgt (stable LDS) + registers only: no barrier needed. ----
  {
    float b2v[2][4];   // [t][e] for c = nv*32 + t*16 + r
#pragma unroll
    for (int t = 0; t < 2; ++t) {
      const int c = nv*32 + t*16 + r;
#pragma unroll
      for (int e = 0; e < 4; ++e) b2v[t][e] = b2[e*256 + c];
    }
    float* ob = out + (size_t)b * C_DIM * S_DIM + s0;
#pragma unroll
    for (int Mt = 0; Mt < 4; ++Mt) {
      const int pb = mh*64 + Mt*16 + q*4;
      f32x4 wv4[4];
#pragma unroll
      for (int reg = 0; reg < 4; ++reg)
        wv4[reg] = *(const f32x4*)(&Wgt[(pb + reg)*4]);
#pragma unroll
      for (int t = 0; t < 2; ++t) {
        const int c = nv*32 + t*16 + r;
        f32x4 v = oacc[Mt][t];
#pragma unroll
        for (int reg = 0; reg < 4; ++reg)
          v[reg] += wv4[reg][0]*b2v[t][0] + wv4[reg][1]*b2v[t][1]
                  + wv4[reg][2]*b2v[t][2] + wv4[reg][3]*b2v[t][3];
        const float4 xr = *(const float4*)(xb + (size_t)c*S_DIM + pb);
        float4 res;
        res.x = v[0] + xr.x; res.y = v[1] + xr.y;
        res.z = v[2] + xr.z; res.w = v[3] + xr.w;
        *(float4*)(ob + (size_t)c*S_DIM + pb) = res;
      }
    }
  }
}

extern "C" void kernel_launch(void* const* d_in, const int* in_sizes, int n_in,
                              void* d_out, int out_size, void* d_ws, size_t ws_size,
                              hipStream_t stream)
{
  (void)in_sizes; (void)n_in; (void)out_size; (void)ws_size;
  const float* x      = (const float*)d_in[0];
  const float* gate_w = (const float*)d_in[1];
  const float* gate_b = (const float*)d_in[2];
  const float* w1     = (const float*)d_in[3];
  const float* b1     = (const float*)d_in[4];
  const float* w2     = (const float*)d_in[5];
  const float* b2     = (const float*)d_in[6];
  float* out = (float*)d_out;
  __hip_bfloat16* wpack = (__hip_bfloat16*)d_ws;   // needs 1 MiB of scratch

  prepack_kernel<<<256, 256, 0, stream>>>(w1, w2, wpack);
  moe_fused_kernel<<<256, 1024, 0, stream>>>(x, gate_w, gate_b, b1, b2, wpack, out);
}